// Round 9
// baseline (302.224 us; speedup 1.0000x reference)
//
#include <hip/hip_runtime.h>
#include <stdint.h>

typedef __bf16 bf16x8 __attribute__((ext_vector_type(8)));
typedef float  floatx4 __attribute__((ext_vector_type(4)));
typedef float  floatx2 __attribute__((ext_vector_type(2)));
typedef __fp16 h2 __attribute__((ext_vector_type(2)));

__device__ __forceinline__ unsigned short f2b(float x){
    unsigned u = __float_as_uint(x);
    u = u + 0x7FFFu + ((u >> 16) & 1u);          // RNE
    return (unsigned short)(u >> 16);
}
__device__ __forceinline__ float b2f(unsigned short h){
    return __uint_as_float(((unsigned)h) << 16);
}
__device__ __forceinline__ unsigned char f2f8(float x){
    int p = __builtin_amdgcn_cvt_pk_fp8_f32(x, x, 0, false);
    return (unsigned char)(p & 0xff);
}

// ================= CSR build: reservation counting sort (single pass) =========
__global__ __launch_bounds__(256) void k_scatter2(const int* __restrict__ src,
                                                  const int* __restrict__ dst,
                                                  int* __restrict__ gcur,
                                                  unsigned* __restrict__ slab,
                                                  int E_, int nbins){
    __shared__ int h[1024];
    __shared__ unsigned wbuf[4096];
    __shared__ unsigned short bbuf[4096];
    int t = threadIdx.x, blk = blockIdx.x;
    for (int i = t; i < nbins; i += 256) h[i] = 0;
    __syncthreads();
    int base = blk * 4096;
    int valid = E_ - base; if (valid > 4096) valid = 4096;
    #pragma unroll
    for (int j = 0; j < 4; j++){
        int li = (j * 256 + t) * 4;
        int e = base + li;
        if (e < E_){
            int4 d = *(const int4*)(dst + e);
            int4 s = *(const int4*)(src + e);
            wbuf[li + 0] = ((unsigned)(d.x & 127) << 25) | (unsigned)s.x;
            wbuf[li + 1] = ((unsigned)(d.y & 127) << 25) | (unsigned)s.y;
            wbuf[li + 2] = ((unsigned)(d.z & 127) << 25) | (unsigned)s.z;
            wbuf[li + 3] = ((unsigned)(d.w & 127) << 25) | (unsigned)s.w;
            bbuf[li + 0] = (unsigned short)(d.x >> 7);
            bbuf[li + 1] = (unsigned short)(d.y >> 7);
            bbuf[li + 2] = (unsigned short)(d.z >> 7);
            bbuf[li + 3] = (unsigned short)(d.w >> 7);
            atomicAdd(&h[d.x >> 7], 1);
            atomicAdd(&h[d.y >> 7], 1);
            atomicAdd(&h[d.z >> 7], 1);
            atomicAdd(&h[d.w >> 7], 1);
        }
    }
    __syncthreads();
    for (int i = t; i < nbins; i += 256){
        int hv = h[i];
        h[i] = hv ? atomicAdd(&gcur[i], hv) : 0;
    }
    __syncthreads();
    for (int i = t; i < valid; i += 256){
        int bin = bbuf[i];
        int p = atomicAdd(&h[bin], 1);
        slab[(size_t)bin * 4096 + p] = wbuf[i];
    }
}

__global__ __launch_bounds__(256) void k_binsort(const unsigned* __restrict__ slab,
                                                 const int* __restrict__ gcur,
                                                 int* __restrict__ csr,
                                                 int* __restrict__ cnt,
                                                 int* __restrict__ off,
                                                 float* __restrict__ dinv,
                                                 int n, int nbins){
    int b = blockIdx.x, t = threadIdx.x;
    __shared__ int sv[1024], sp[256];
    #pragma unroll
    for (int k = 0; k < 4; k++){
        int i = t * 4 + k;
        sv[i] = (i < nbins) ? gcur[i] : 0;
    }
    __syncthreads();
    int a0 = sv[t * 4], a1 = sv[t * 4 + 1], a2 = sv[t * 4 + 2], a3 = sv[t * 4 + 3];
    sp[t] = a0 + a1 + a2 + a3;
    __syncthreads();
    for (int o = 1; o < 256; o <<= 1){
        int v = (t >= o) ? sp[t - o] : 0;
        __syncthreads();
        sp[t] += v;
        __syncthreads();
    }
    int basep = t ? sp[t - 1] : 0;
    sv[t * 4]     = basep;
    sv[t * 4 + 1] = basep + a0;
    sv[t * 4 + 2] = basep + a0 + a1;
    sv[t * 4 + 3] = basep + a0 + a1 + a2;
    __syncthreads();
    int s0 = sv[b];
    int len = gcur[b];
    if (len > 4096) len = 4096;
    const unsigned* seg = slab + (size_t)b * 4096;
    __shared__ int cl[128], sc[128], cur[128];
    __shared__ unsigned buf[4096], outb[4096];
    if (t < 128){ cl[t] = 0; cur[t] = 0; }
    __syncthreads();
    for (int i = t; i < len; i += 256) buf[i] = seg[i];
    __syncthreads();
    for (int i = t; i < len; i += 256) atomicAdd(&cl[buf[i] >> 25], 1);
    __syncthreads();
    if (t < 128) sc[t] = cl[t];
    __syncthreads();
    for (int o = 1; o < 128; o <<= 1){
        int v = 0;
        if (t < 128 && t >= o) v = sc[t - o];
        __syncthreads();
        if (t < 128) sc[t] += v;
        __syncthreads();
    }
    for (int i = t; i < len; i += 256){
        unsigned w = buf[i];
        int nd = (int)(w >> 25);
        int p = (sc[nd] - cl[nd]) + atomicAdd(&cur[nd], 1);
        outb[p] = w & 0x1FFFFFFu;
    }
    __syncthreads();
    // NEW: sort each node's segment by src (ascending). Thread t owns node t's
    // disjoint segment -> race-free. Sequential-ish gathers downstream: all
    // concurrent agg waves at similar list-fraction read nearby rows -> L2 hits.
    if (t < 128){
        int beg = sc[t] - cl[t], end = sc[t];
        for (int a = beg + 1; a < end; a++){
            unsigned key = outb[a];
            int p = a - 1;
            while (p >= beg && outb[p] > key){ outb[p + 1] = outb[p]; p--; }
            outb[p + 1] = key;
        }
    }
    __syncthreads();
    for (int i = t; i < len; i += 256) csr[s0 + i] = (int)outb[i];
    if (t < 128){
        int node = b * 128 + t;
        if (node < n){
            cnt[node] = cl[t];
            off[node] = s0 + (sc[t] - cl[t]);
            dinv[node] = rsqrtf((float)cl[t] + 1.0f);
        }
    }
}

// -------- init: W1 -> MFMA B-frag order; W2 -> packed f16 pairs; zero gcur ----
__global__ __launch_bounds__(256) void k_init(const float* __restrict__ W1,
                                              const float* __restrict__ W2,
                                              unsigned short* __restrict__ wf1,
                                              unsigned* __restrict__ w2p,
                                              int* __restrict__ gcur, int nbins){
    int blk = blockIdx.x, t = threadIdx.x;
    if (blk == 24){
        for (int i = t; i < nbins; i += 256) gcur[i] = 0;
        return;
    }
    int f = blk * 256 + t;
    if (f < 2048){
        int lane = f & 63;
        int ctkc = f >> 6;
        int kc = ctkc & 3, ct = ctkc >> 2;
        int col = ct * 16 + (lane & 15);
        int k0  = kc * 32 + (lane >> 4) * 8;
        unsigned short* d = wf1 + (size_t)f * 8;
        #pragma unroll
        for (int j = 0; j < 8; j++) d[j] = f2b(W1[(k0 + j) * 128 + col]);
    } else if (f < 2048 + 4096){
        int lf = f - 2048;
        int kp = lf >> 6, lane = lf & 63;
        h2 p = __builtin_amdgcn_cvt_pkrtz(W2[(2 * kp) * 64 + lane],
                                          W2[(2 * kp + 1) * 64 + lane]);
        w2p[lf] = __builtin_bit_cast(unsigned, p);
    }
}

// ---------------- GEMM1: hs1 = fp8( (x @ W1) * dinv[row] ), row-major ---------
__global__ __launch_bounds__(256) void k_gemm1(const float* __restrict__ x,
                                               const unsigned short* __restrict__ wf,
                                               const float* __restrict__ dinv,
                                               unsigned char* __restrict__ hs, int n){
    __shared__ unsigned short Wl[16384];
    __shared__ unsigned short Al[64 * 136];
    int t = threadIdx.x;
    long rowBase = (long)blockIdx.x * 64;
    {
        const uint4* s4 = (const uint4*)wf;
        uint4* d4 = (uint4*)Wl;
        #pragma unroll
        for (int i = 0; i < 8; i++) d4[t + i * 256] = s4[t + i * 256];
    }
    {
        const float4* xs = (const float4*)(x + rowBase * 128);
        #pragma unroll
        for (int k = 0; k < 8; k++){
            int i = t + k * 256;
            int r = i >> 5, c4 = (i & 31) << 2;
            float4 v = make_float4(0.f, 0.f, 0.f, 0.f);
            if (rowBase + r < n) v = xs[i];
            unsigned lo = (unsigned)f2b(v.x) | ((unsigned)f2b(v.y) << 16);
            unsigned hi = (unsigned)f2b(v.z) | ((unsigned)f2b(v.w) << 16);
            *(uint2*)&Al[r * 136 + c4] = make_uint2(lo, hi);
        }
    }
    __syncthreads();
    int w = t >> 6, lane = t & 63, lr = lane & 15, q = lane >> 4;
    floatx4 zero = {0.f, 0.f, 0.f, 0.f};
    floatx4 acc[8];
    #pragma unroll
    for (int ct = 0; ct < 8; ct++) acc[ct] = zero;
    #pragma unroll
    for (int kc = 0; kc < 4; kc++){
        bf16x8 af = *(const bf16x8*)&Al[(w * 16 + lr) * 136 + kc * 32 + q * 8];
        #pragma unroll
        for (int ct = 0; ct < 8; ct++){
            bf16x8 bf = *(const bf16x8*)&Wl[((ct * 4 + kc) * 64 + lane) * 8];
            acc[ct] = __builtin_amdgcn_mfma_f32_16x16x32_bf16(af, bf, acc[ct], 0, 0, 0);
        }
    }
    long r0 = rowBase + w * 16 + q * 4;
    #pragma unroll
    for (int r = 0; r < 4; r++){
        long row = r0 + r;
        if (row >= n) continue;
        float dv = dinv[row];
        unsigned char* orow = hs + row * 128 + lr;
        #pragma unroll
        for (int ct = 0; ct < 8; ct++) orow[ct * 16] = f2f8(acc[ct][r] * dv);
    }
}

// ---- fused agg1 + gemm2: 2 nodes/wave, UNROLL 8 (16 rows in flight/wave) ----
__global__ __launch_bounds__(256) void k_agg1g2(const unsigned char* __restrict__ hs,
                                                const int* __restrict__ off,
                                                const int* __restrict__ cnt,
                                                const int* __restrict__ csr,
                                                const float* __restrict__ dinv,
                                                const float* __restrict__ b1,
                                                const unsigned* __restrict__ w2p,
                                                unsigned short* __restrict__ hs2,
                                                int n, int nwaves){
    __shared__ unsigned W2l[4096];     // 16 KB packed half2 [kp][out]
    __shared__ unsigned zp[4][2][64];  // packed half2 z row per wave/half
    int t = threadIdx.x;
    {
        const uint4* w4 = (const uint4*)w2p;
        uint4* d4 = (uint4*)W2l;
        #pragma unroll
        for (int i = 0; i < 4; i++) d4[t + i * 256] = w4[t + i * 256];
    }
    __syncthreads();
    int wband = t >> 6, lane = t & 63;
    int half = lane >> 5, hl = lane & 31;
    unsigned hb = (unsigned)(hl * 4);
    float4 bb = ((const float4*)b1)[hl];          // features 4hl..4hl+3
    int npairs = (n + 1) >> 1;
    for (int pw = blockIdx.x * 4 + wband; pw < npairs; pw += nwaves){
        int wid = pw * 2 + half;
        if (wid < n){
            size_t i = (size_t)wid;
            int start = off[wid], c = cnt[wid];
            unsigned v0 = *(const unsigned*)(hs + i * 128 + hb);
            floatx2 a01 = __builtin_amdgcn_cvt_pk_f32_fp8((int)v0, false);
            floatx2 a23 = __builtin_amdgcn_cvt_pk_f32_fp8((int)v0, true);
            int j = 0;
            for (; j + 8 <= c; j += 8){
                int i0 = start + j;
                unsigned o0 = (unsigned)__builtin_nontemporal_load(csr + i0 + 0) * 128u + hb;
                unsigned o1 = (unsigned)__builtin_nontemporal_load(csr + i0 + 1) * 128u + hb;
                unsigned o2 = (unsigned)__builtin_nontemporal_load(csr + i0 + 2) * 128u + hb;
                unsigned o3 = (unsigned)__builtin_nontemporal_load(csr + i0 + 3) * 128u + hb;
                unsigned o4 = (unsigned)__builtin_nontemporal_load(csr + i0 + 4) * 128u + hb;
                unsigned o5 = (unsigned)__builtin_nontemporal_load(csr + i0 + 5) * 128u + hb;
                unsigned o6 = (unsigned)__builtin_nontemporal_load(csr + i0 + 6) * 128u + hb;
                unsigned o7 = (unsigned)__builtin_nontemporal_load(csr + i0 + 7) * 128u + hb;
                unsigned w0 = *(const unsigned*)(hs + o0);
                unsigned w1 = *(const unsigned*)(hs + o1);
                unsigned w2 = *(const unsigned*)(hs + o2);
                unsigned w3 = *(const unsigned*)(hs + o3);
                unsigned w4 = *(const unsigned*)(hs + o4);
                unsigned w5 = *(const unsigned*)(hs + o5);
                unsigned w6 = *(const unsigned*)(hs + o6);
                unsigned w7 = *(const unsigned*)(hs + o7);
                a01 += __builtin_amdgcn_cvt_pk_f32_fp8((int)w0, false);
                a23 += __builtin_amdgcn_cvt_pk_f32_fp8((int)w0, true);
                a01 += __builtin_amdgcn_cvt_pk_f32_fp8((int)w1, false);
                a23 += __builtin_amdgcn_cvt_pk_f32_fp8((int)w1, true);
                a01 += __builtin_amdgcn_cvt_pk_f32_fp8((int)w2, false);
                a23 += __builtin_amdgcn_cvt_pk_f32_fp8((int)w2, true);
                a01 += __builtin_amdgcn_cvt_pk_f32_fp8((int)w3, false);
                a23 += __builtin_amdgcn_cvt_pk_f32_fp8((int)w3, true);
                a01 += __builtin_amdgcn_cvt_pk_f32_fp8((int)w4, false);
                a23 += __builtin_amdgcn_cvt_pk_f32_fp8((int)w4, true);
                a01 += __builtin_amdgcn_cvt_pk_f32_fp8((int)w5, false);
                a23 += __builtin_amdgcn_cvt_pk_f32_fp8((int)w5, true);
                a01 += __builtin_amdgcn_cvt_pk_f32_fp8((int)w6, false);
                a23 += __builtin_amdgcn_cvt_pk_f32_fp8((int)w6, true);
                a01 += __builtin_amdgcn_cvt_pk_f32_fp8((int)w7, false);
                a23 += __builtin_amdgcn_cvt_pk_f32_fp8((int)w7, true);
            }
            for (; j + 4 <= c; j += 4){
                int i0 = start + j;
                unsigned o0 = (unsigned)__builtin_nontemporal_load(csr + i0 + 0) * 128u + hb;
                unsigned o1 = (unsigned)__builtin_nontemporal_load(csr + i0 + 1) * 128u + hb;
                unsigned o2 = (unsigned)__builtin_nontemporal_load(csr + i0 + 2) * 128u + hb;
                unsigned o3 = (unsigned)__builtin_nontemporal_load(csr + i0 + 3) * 128u + hb;
                unsigned w0 = *(const unsigned*)(hs + o0);
                unsigned w1 = *(const unsigned*)(hs + o1);
                unsigned w2 = *(const unsigned*)(hs + o2);
                unsigned w3 = *(const unsigned*)(hs + o3);
                a01 += __builtin_amdgcn_cvt_pk_f32_fp8((int)w0, false);
                a23 += __builtin_amdgcn_cvt_pk_f32_fp8((int)w0, true);
                a01 += __builtin_amdgcn_cvt_pk_f32_fp8((int)w1, false);
                a23 += __builtin_amdgcn_cvt_pk_f32_fp8((int)w1, true);
                a01 += __builtin_amdgcn_cvt_pk_f32_fp8((int)w2, false);
                a23 += __builtin_amdgcn_cvt_pk_f32_fp8((int)w2, true);
                a01 += __builtin_amdgcn_cvt_pk_f32_fp8((int)w3, false);
                a23 += __builtin_amdgcn_cvt_pk_f32_fp8((int)w3, true);
            }
            for (; j < c; j++){
                unsigned o = (unsigned)__builtin_nontemporal_load(csr + start + j) * 128u + hb;
                unsigned wv = *(const unsigned*)(hs + o);
                a01 += __builtin_amdgcn_cvt_pk_f32_fp8((int)wv, false);
                a23 += __builtin_amdgcn_cvt_pk_f32_fp8((int)wv, true);
            }
            float dv = dinv[wid];
            float z0 = fmaxf(fmaf(dv, a01.x, bb.x), 0.f);
            float z1 = fmaxf(fmaf(dv, a01.y, bb.y), 0.f);
            float z2 = fmaxf(fmaf(dv, a23.x, bb.z), 0.f);
            float z3 = fmaxf(fmaf(dv, a23.y, bb.w), 0.f);
            zp[wband][half][hl * 2]     = __builtin_bit_cast(unsigned, __builtin_amdgcn_cvt_pkrtz(z0, z1));
            zp[wband][half][hl * 2 + 1] = __builtin_bit_cast(unsigned, __builtin_amdgcn_cvt_pkrtz(z2, z3));
            float acc0 = 0.f, acc1 = 0.f;
            #pragma unroll 16
            for (int kp = 0; kp < 64; kp++){
                h2 za = __builtin_bit_cast(h2, zp[wband][half][kp]);
                h2 wa = __builtin_bit_cast(h2, W2l[kp * 64 + hl]);
                h2 wb = __builtin_bit_cast(h2, W2l[kp * 64 + hl + 32]);
                acc0 = __builtin_amdgcn_fdot2(za, wa, acc0, false);
                acc1 = __builtin_amdgcn_fdot2(za, wb, acc1, false);
            }
            hs2[i * 64 + hl]      = f2b(acc0 * dv);
            hs2[i * 64 + hl + 32] = f2b(acc1 * dv);
        }
    }
}

// ---- aggregation layer 2: 4 nodes/wave, UNROLL 8 (32 rows in flight/wave) ----
__global__ __launch_bounds__(256) void k_agg2(const unsigned short* __restrict__ hs,
                                              const int* __restrict__ off,
                                              const int* __restrict__ cnt,
                                              const int* __restrict__ csr,
                                              const float* __restrict__ dinv,
                                              const float* __restrict__ b,
                                              unsigned short* __restrict__ z, int n){
    int wv = (blockIdx.x * 256 + threadIdx.x) >> 6;
    int lane = threadIdx.x & 63;
    int quarter = lane >> 4, ql = lane & 15;
    int node = wv * 4 + quarter;
    if (node >= n) return;
    size_t i = (size_t)node;
    const unsigned char* hb8 = (const unsigned char*)hs;
    unsigned qb = (unsigned)(ql * 8);
    int start = off[node], c = cnt[node];
    uint2 v0 = *(const uint2*)(hs + i * 64 + ql * 4);
    float a0 = b2f((unsigned short)v0.x), a1 = b2f((unsigned short)(v0.x >> 16));
    float a2 = b2f((unsigned short)v0.y), a3 = b2f((unsigned short)(v0.y >> 16));
    int j = 0;
    for (; j + 8 <= c; j += 8){
        int i0 = start + j;
        unsigned o0 = (unsigned)__builtin_nontemporal_load(csr + i0 + 0) * 128u + qb;
        unsigned o1 = (unsigned)__builtin_nontemporal_load(csr + i0 + 1) * 128u + qb;
        unsigned o2 = (unsigned)__builtin_nontemporal_load(csr + i0 + 2) * 128u + qb;
        unsigned o3 = (unsigned)__builtin_nontemporal_load(csr + i0 + 3) * 128u + qb;
        unsigned o4 = (unsigned)__builtin_nontemporal_load(csr + i0 + 4) * 128u + qb;
        unsigned o5 = (unsigned)__builtin_nontemporal_load(csr + i0 + 5) * 128u + qb;
        unsigned o6 = (unsigned)__builtin_nontemporal_load(csr + i0 + 6) * 128u + qb;
        unsigned o7 = (unsigned)__builtin_nontemporal_load(csr + i0 + 7) * 128u + qb;
        uint2 w0 = *(const uint2*)(hb8 + o0);
        uint2 w1 = *(const uint2*)(hb8 + o1);
        uint2 w2 = *(const uint2*)(hb8 + o2);
        uint2 w3 = *(const uint2*)(hb8 + o3);
        uint2 w4 = *(const uint2*)(hb8 + o4);
        uint2 w5 = *(const uint2*)(hb8 + o5);
        uint2 w6 = *(const uint2*)(hb8 + o6);
        uint2 w7 = *(const uint2*)(hb8 + o7);
        a0 += b2f((unsigned short)w0.x); a1 += b2f((unsigned short)(w0.x >> 16));
        a2 += b2f((unsigned short)w0.y); a3 += b2f((unsigned short)(w0.y >> 16));
        a0 += b2f((unsigned short)w1.x); a1 += b2f((unsigned short)(w1.x >> 16));
        a2 += b2f((unsigned short)w1.y); a3 += b2f((unsigned short)(w1.y >> 16));
        a0 += b2f((unsigned short)w2.x); a1 += b2f((unsigned short)(w2.x >> 16));
        a2 += b2f((unsigned short)w2.y); a3 += b2f((unsigned short)(w2.y >> 16));
        a0 += b2f((unsigned short)w3.x); a1 += b2f((unsigned short)(w3.x >> 16));
        a2 += b2f((unsigned short)w3.y); a3 += b2f((unsigned short)(w3.y >> 16));
        a0 += b2f((unsigned short)w4.x); a1 += b2f((unsigned short)(w4.x >> 16));
        a2 += b2f((unsigned short)w4.y); a3 += b2f((unsigned short)(w4.y >> 16));
        a0 += b2f((unsigned short)w5.x); a1 += b2f((unsigned short)(w5.x >> 16));
        a2 += b2f((unsigned short)w5.y); a3 += b2f((unsigned short)(w5.y >> 16));
        a0 += b2f((unsigned short)w6.x); a1 += b2f((unsigned short)(w6.x >> 16));
        a2 += b2f((unsigned short)w6.y); a3 += b2f((unsigned short)(w6.y >> 16));
        a0 += b2f((unsigned short)w7.x); a1 += b2f((unsigned short)(w7.x >> 16));
        a2 += b2f((unsigned short)w7.y); a3 += b2f((unsigned short)(w7.y >> 16));
    }
    for (; j + 4 <= c; j += 4){
        int i0 = start + j;
        unsigned o0 = (unsigned)__builtin_nontemporal_load(csr + i0 + 0) * 128u + qb;
        unsigned o1 = (unsigned)__builtin_nontemporal_load(csr + i0 + 1) * 128u + qb;
        unsigned o2 = (unsigned)__builtin_nontemporal_load(csr + i0 + 2) * 128u + qb;
        unsigned o3 = (unsigned)__builtin_nontemporal_load(csr + i0 + 3) * 128u + qb;
        uint2 w0 = *(const uint2*)(hb8 + o0);
        uint2 w1 = *(const uint2*)(hb8 + o1);
        uint2 w2 = *(const uint2*)(hb8 + o2);
        uint2 w3 = *(const uint2*)(hb8 + o3);
        a0 += b2f((unsigned short)w0.x); a1 += b2f((unsigned short)(w0.x >> 16));
        a2 += b2f((unsigned short)w0.y); a3 += b2f((unsigned short)(w0.y >> 16));
        a0 += b2f((unsigned short)w1.x); a1 += b2f((unsigned short)(w1.x >> 16));
        a2 += b2f((unsigned short)w1.y); a3 += b2f((unsigned short)(w1.y >> 16));
        a0 += b2f((unsigned short)w2.x); a1 += b2f((unsigned short)(w2.x >> 16));
        a2 += b2f((unsigned short)w2.y); a3 += b2f((unsigned short)(w2.y >> 16));
        a0 += b2f((unsigned short)w3.x); a1 += b2f((unsigned short)(w3.x >> 16));
        a2 += b2f((unsigned short)w3.y); a3 += b2f((unsigned short)(w3.y >> 16));
    }
    for (; j < c; j++){
        unsigned o = (unsigned)__builtin_nontemporal_load(csr + start + j) * 128u + qb;
        uint2 wv2 = *(const uint2*)(hb8 + o);
        a0 += b2f((unsigned short)wv2.x); a1 += b2f((unsigned short)(wv2.x >> 16));
        a2 += b2f((unsigned short)wv2.y); a3 += b2f((unsigned short)(wv2.y >> 16));
    }
    float dv = dinv[node];
    float4 bb = ((const float4*)b)[ql];
    float r0 = fmaf(dv, a0, bb.x);
    float r1 = fmaf(dv, a1, bb.y);
    float r2 = fmaf(dv, a2, bb.z);
    float r3 = fmaf(dv, a3, bb.w);
    uint2 ov;
    ov.x = (unsigned)f2b(r0) | ((unsigned)f2b(r1) << 16);
    ov.y = (unsigned)f2b(r2) | ((unsigned)f2b(r3) << 16);
    *(uint2*)(z + i * 64 + ql * 4) = ov;
}

// ------- decode: out[e] = dot(z2[s], z2[t]); 4 edges/wave, uint2 loads ---------
__global__ __launch_bounds__(256) void k_decode(const unsigned short* __restrict__ z,
                                                const int* __restrict__ es,
                                                const int* __restrict__ et,
                                                float* __restrict__ out, int m){
    int wv = (blockIdx.x * 256 + threadIdx.x) >> 6;
    int lane = threadIdx.x & 63;
    int e = wv * 4 + (lane >> 4);
    int ql = lane & 15;
    float p = 0.f;
    if (e < m){
        size_t s = (size_t)es[e], t2 = (size_t)et[e];
        uint2 vs = *(const uint2*)(z + s * 64 + ql * 4);
        uint2 vt = *(const uint2*)(z + t2 * 64 + ql * 4);
        p = b2f((unsigned short)vs.x) * b2f((unsigned short)vt.x)
          + b2f((unsigned short)(vs.x >> 16)) * b2f((unsigned short)(vt.x >> 16))
          + b2f((unsigned short)vs.y) * b2f((unsigned short)vt.y)
          + b2f((unsigned short)(vs.y >> 16)) * b2f((unsigned short)(vt.y >> 16));
    }
    #pragma unroll
    for (int o = 8; o > 0; o >>= 1) p += __shfl_xor(p, o);
    if (ql == 0 && e < m) out[e] = p;
}

// ---------------- launcher (round-0 workspace layout, 46.07MB) ----------------

extern "C" void kernel_launch(void* const* d_in, const int* in_sizes, int n_in,
                              void* d_out, int out_size, void* d_ws, size_t ws_size,
                              hipStream_t stream){
    const float* x   = (const float*)d_in[0];
    const int*   ei  = (const int*)d_in[1];
    const int*   eli = (const int*)d_in[2];
    const float* W1  = (const float*)d_in[3];
    const float* b1  = (const float*)d_in[4];
    const float* W2  = (const float*)d_in[5];
    const float* b2  = (const float*)d_in[6];
    float* out = (float*)d_out;

    int N_  = in_sizes[0] / 128;
    int E_  = in_sizes[1] / 2;
    int EL_ = in_sizes[2] / 2;
    int NBINS = (N_ + 127) >> 7;           // 782 for N=100k (must be <= 1024)
    const int EPB = 4096;
    int NBLK = (E_ + EPB - 1) / EPB;       // 391 for E=1.6M

    char* w = (char*)d_ws;
    size_t o = 0;
    auto alloc = [&](size_t bytes) -> size_t {
        size_t r = o; o += (bytes + 511) & ~(size_t)511; return r;
    };
    size_t o_cnt  = alloc((size_t)N_ * 4);
    size_t o_off  = alloc((size_t)N_ * 4);
    size_t o_dinv = alloc((size_t)N_ * 4);
    size_t o_gcur = alloc((size_t)NBINS * 4);
    size_t o_csr  = alloc((size_t)E_ * 4);
    size_t o_wf1  = alloc(16384 * 2);
    size_t o_w2p  = alloc(4096 * 4);
    size_t o_slab = alloc((size_t)NBINS * 4096 * 4);   // 12.8MB; also z2 after binsort+agg2
    size_t o_hs1  = alloc((size_t)N_ * 128);           // fp8 table, 12.8MB
    size_t o_hs2  = alloc((size_t)N_ * 64 * 2);        // bf16 table, 12.8MB

    int* cnt  = (int*)(w + o_cnt);
    int* off  = (int*)(w + o_off);
    float* dinv = (float*)(w + o_dinv);
    int* gcur = (int*)(w + o_gcur);
    int* csr  = (int*)(w + o_csr);
    unsigned short* wf1 = (unsigned short*)(w + o_wf1);
    unsigned* w2p = (unsigned*)(w + o_w2p);
    unsigned* slab = (unsigned*)(w + o_slab);
    unsigned char* hs1 = (unsigned char*)(w + o_hs1);
    unsigned short* hs2 = (unsigned short*)(w + o_hs2);
    unsigned short* z2  = (unsigned short*)(w + o_slab);  // slab dead after binsort

    const int AGG1_BLOCKS = 2048;          // 8 blocks/CU (18KB LDS) -> 32 waves/CU
    int nwaves = AGG1_BLOCKS * 4;

    k_init    <<<25, 256, 0, stream>>>(W1, W2, wf1, w2p, gcur, NBINS);
    k_scatter2<<<NBLK, 256, 0, stream>>>(ei, ei + E_, gcur, slab, E_, NBINS);
    k_binsort <<<NBINS, 256, 0, stream>>>(slab, gcur, csr, cnt, off, dinv, N_, NBINS);
    k_gemm1   <<<(N_ + 63) / 64, 256, 0, stream>>>(x, wf1, dinv, hs1, N_);
    k_agg1g2  <<<AGG1_BLOCKS, 256, 0, stream>>>(hs1, off, cnt, csr, dinv, b1, w2p, hs2, N_, nwaves);
    k_agg2    <<<(N_ + 15) / 16, 256, 0, stream>>>(hs2, off, cnt, csr, dinv, b2, z2, N_);
    k_decode  <<<(EL_ + 15) / 16, 256, 0, stream>>>(z2, eli, eli + EL_, out, EL_);
}

// Round 10
// 261.161 us; speedup vs baseline: 1.1572x; 1.1572x over previous
//
#include <hip/hip_runtime.h>
#include <stdint.h>

typedef __bf16 bf16x8 __attribute__((ext_vector_type(8)));
typedef float  floatx4 __attribute__((ext_vector_type(4)));
typedef float  floatx2 __attribute__((ext_vector_type(2)));
typedef __fp16 h2 __attribute__((ext_vector_type(2)));

__device__ __forceinline__ unsigned short f2b(float x){
    unsigned u = __float_as_uint(x);
    u = u + 0x7FFFu + ((u >> 16) & 1u);          // RNE
    return (unsigned short)(u >> 16);
}
__device__ __forceinline__ float b2f(unsigned short h){
    return __uint_as_float(((unsigned)h) << 16);
}
__device__ __forceinline__ unsigned char f2f8(float x){
    int p = __builtin_amdgcn_cvt_pk_fp8_f32(x, x, 0, false);
    return (unsigned char)(p & 0xff);
}

// ================= CSR build: reservation counting sort (single pass) =========
__global__ __launch_bounds__(256) void k_scatter2(const int* __restrict__ src,
                                                  const int* __restrict__ dst,
                                                  int* __restrict__ gcur,
                                                  unsigned* __restrict__ slab,
                                                  int E_, int nbins){
    __shared__ int h[1024];
    __shared__ unsigned wbuf[4096];
    __shared__ unsigned short bbuf[4096];
    int t = threadIdx.x, blk = blockIdx.x;
    for (int i = t; i < nbins; i += 256) h[i] = 0;
    __syncthreads();
    int base = blk * 4096;
    int valid = E_ - base; if (valid > 4096) valid = 4096;
    #pragma unroll
    for (int j = 0; j < 4; j++){
        int li = (j * 256 + t) * 4;
        int e = base + li;
        if (e < E_){
            int4 d = *(const int4*)(dst + e);
            int4 s = *(const int4*)(src + e);
            wbuf[li + 0] = ((unsigned)(d.x & 127) << 25) | (unsigned)s.x;
            wbuf[li + 1] = ((unsigned)(d.y & 127) << 25) | (unsigned)s.y;
            wbuf[li + 2] = ((unsigned)(d.z & 127) << 25) | (unsigned)s.z;
            wbuf[li + 3] = ((unsigned)(d.w & 127) << 25) | (unsigned)s.w;
            bbuf[li + 0] = (unsigned short)(d.x >> 7);
            bbuf[li + 1] = (unsigned short)(d.y >> 7);
            bbuf[li + 2] = (unsigned short)(d.z >> 7);
            bbuf[li + 3] = (unsigned short)(d.w >> 7);
            atomicAdd(&h[d.x >> 7], 1);
            atomicAdd(&h[d.y >> 7], 1);
            atomicAdd(&h[d.z >> 7], 1);
            atomicAdd(&h[d.w >> 7], 1);
        }
    }
    __syncthreads();
    for (int i = t; i < nbins; i += 256){
        int hv = h[i];
        h[i] = hv ? atomicAdd(&gcur[i], hv) : 0;
    }
    __syncthreads();
    for (int i = t; i < valid; i += 256){
        int bin = bbuf[i];
        int p = atomicAdd(&h[bin], 1);
        slab[(size_t)bin * 4096 + p] = wbuf[i];
    }
}

__global__ __launch_bounds__(256) void k_binsort(const unsigned* __restrict__ slab,
                                                 const int* __restrict__ gcur,
                                                 int* __restrict__ csr,
                                                 int* __restrict__ cnt,
                                                 int* __restrict__ off,
                                                 float* __restrict__ dinv,
                                                 int n, int nbins){
    int b = blockIdx.x, t = threadIdx.x;
    __shared__ int sv[1024], sp[256];
    #pragma unroll
    for (int k = 0; k < 4; k++){
        int i = t * 4 + k;
        sv[i] = (i < nbins) ? gcur[i] : 0;
    }
    __syncthreads();
    int a0 = sv[t * 4], a1 = sv[t * 4 + 1], a2 = sv[t * 4 + 2], a3 = sv[t * 4 + 3];
    sp[t] = a0 + a1 + a2 + a3;
    __syncthreads();
    for (int o = 1; o < 256; o <<= 1){
        int v = (t >= o) ? sp[t - o] : 0;
        __syncthreads();
        sp[t] += v;
        __syncthreads();
    }
    int basep = t ? sp[t - 1] : 0;
    sv[t * 4]     = basep;
    sv[t * 4 + 1] = basep + a0;
    sv[t * 4 + 2] = basep + a0 + a1;
    sv[t * 4 + 3] = basep + a0 + a1 + a2;
    __syncthreads();
    int s0 = sv[b];
    int len = gcur[b];
    if (len > 4096) len = 4096;
    const unsigned* seg = slab + (size_t)b * 4096;
    __shared__ int cl[128], sc[128], cur[128];
    __shared__ unsigned buf[4096], outb[4096];
    if (t < 128){ cl[t] = 0; cur[t] = 0; }
    __syncthreads();
    for (int i = t; i < len; i += 256) buf[i] = seg[i];
    __syncthreads();
    for (int i = t; i < len; i += 256) atomicAdd(&cl[buf[i] >> 25], 1);
    __syncthreads();
    if (t < 128) sc[t] = cl[t];
    __syncthreads();
    for (int o = 1; o < 128; o <<= 1){
        int v = 0;
        if (t < 128 && t >= o) v = sc[t - o];
        __syncthreads();
        if (t < 128) sc[t] += v;
        __syncthreads();
    }
    for (int i = t; i < len; i += 256){
        unsigned w = buf[i];
        int nd = (int)(w >> 25);
        int p = (sc[nd] - cl[nd]) + atomicAdd(&cur[nd], 1);
        outb[p] = w & 0x1FFFFFFu;
    }
    __syncthreads();
    for (int i = t; i < len; i += 256) csr[s0 + i] = (int)outb[i];
    if (t < 128){
        int node = b * 128 + t;
        if (node < n){
            cnt[node] = cl[t];
            off[node] = s0 + (sc[t] - cl[t]);
            dinv[node] = rsqrtf((float)cl[t] + 1.0f);
        }
    }
}

// -------- init: W1 -> MFMA B-frag order; W2 -> packed f16 pairs; zero gcur ----
__global__ __launch_bounds__(256) void k_init(const float* __restrict__ W1,
                                              const float* __restrict__ W2,
                                              unsigned short* __restrict__ wf1,
                                              unsigned* __restrict__ w2p,
                                              int* __restrict__ gcur, int nbins){
    int blk = blockIdx.x, t = threadIdx.x;
    if (blk == 24){
        for (int i = t; i < nbins; i += 256) gcur[i] = 0;
        return;
    }
    int f = blk * 256 + t;
    if (f < 2048){
        int lane = f & 63;
        int ctkc = f >> 6;
        int kc = ctkc & 3, ct = ctkc >> 2;
        int col = ct * 16 + (lane & 15);
        int k0  = kc * 32 + (lane >> 4) * 8;
        unsigned short* d = wf1 + (size_t)f * 8;
        #pragma unroll
        for (int j = 0; j < 8; j++) d[j] = f2b(W1[(k0 + j) * 128 + col]);
    } else if (f < 2048 + 4096){
        int lf = f - 2048;
        int kp = lf >> 6, lane = lf & 63;
        h2 p = __builtin_amdgcn_cvt_pkrtz(W2[(2 * kp) * 64 + lane],
                                          W2[(2 * kp + 1) * 64 + lane]);
        w2p[lf] = __builtin_bit_cast(unsigned, p);
    }
}

// ---------------- GEMM1: hs1 = fp8( (x @ W1) * dinv[row] ), row-major ---------
__global__ __launch_bounds__(256) void k_gemm1(const float* __restrict__ x,
                                               const unsigned short* __restrict__ wf,
                                               const float* __restrict__ dinv,
                                               unsigned char* __restrict__ hs, int n){
    __shared__ unsigned short Wl[16384];
    __shared__ unsigned short Al[64 * 136];
    int t = threadIdx.x;
    long rowBase = (long)blockIdx.x * 64;
    {
        const uint4* s4 = (const uint4*)wf;
        uint4* d4 = (uint4*)Wl;
        #pragma unroll
        for (int i = 0; i < 8; i++) d4[t + i * 256] = s4[t + i * 256];
    }
    {
        const float4* xs = (const float4*)(x + rowBase * 128);
        #pragma unroll
        for (int k = 0; k < 8; k++){
            int i = t + k * 256;
            int r = i >> 5, c4 = (i & 31) << 2;
            float4 v = make_float4(0.f, 0.f, 0.f, 0.f);
            if (rowBase + r < n) v = xs[i];
            unsigned lo = (unsigned)f2b(v.x) | ((unsigned)f2b(v.y) << 16);
            unsigned hi = (unsigned)f2b(v.z) | ((unsigned)f2b(v.w) << 16);
            *(uint2*)&Al[r * 136 + c4] = make_uint2(lo, hi);
        }
    }
    __syncthreads();
    int w = t >> 6, lane = t & 63, lr = lane & 15, q = lane >> 4;
    floatx4 zero = {0.f, 0.f, 0.f, 0.f};
    floatx4 acc[8];
    #pragma unroll
    for (int ct = 0; ct < 8; ct++) acc[ct] = zero;
    #pragma unroll
    for (int kc = 0; kc < 4; kc++){
        bf16x8 af = *(const bf16x8*)&Al[(w * 16 + lr) * 136 + kc * 32 + q * 8];
        #pragma unroll
        for (int ct = 0; ct < 8; ct++){
            bf16x8 bf = *(const bf16x8*)&Wl[((ct * 4 + kc) * 64 + lane) * 8];
            acc[ct] = __builtin_amdgcn_mfma_f32_16x16x32_bf16(af, bf, acc[ct], 0, 0, 0);
        }
    }
    long r0 = rowBase + w * 16 + q * 4;
    #pragma unroll
    for (int r = 0; r < 4; r++){
        long row = r0 + r;
        if (row >= n) continue;
        float dv = dinv[row];
        unsigned char* orow = hs + row * 128 + lr;
        #pragma unroll
        for (int ct = 0; ct < 8; ct++) orow[ct * 16] = f2f8(acc[ct][r] * dv);
    }
}

// ---- fused agg1 + gemm2: 2 nodes/wave, UNROLL 8 (16 rows in flight/wave) ----
__global__ __launch_bounds__(256) void k_agg1g2(const unsigned char* __restrict__ hs,
                                                const int* __restrict__ off,
                                                const int* __restrict__ cnt,
                                                const int* __restrict__ csr,
                                                const float* __restrict__ dinv,
                                                const float* __restrict__ b1,
                                                const unsigned* __restrict__ w2p,
                                                unsigned short* __restrict__ hs2,
                                                int n, int nwaves){
    __shared__ unsigned W2l[4096];     // 16 KB packed half2 [kp][out]
    __shared__ unsigned zp[4][2][64];  // packed half2 z row per wave/half
    int t = threadIdx.x;
    {
        const uint4* w4 = (const uint4*)w2p;
        uint4* d4 = (uint4*)W2l;
        #pragma unroll
        for (int i = 0; i < 4; i++) d4[t + i * 256] = w4[t + i * 256];
    }
    __syncthreads();
    int wband = t >> 6, lane = t & 63;
    int half = lane >> 5, hl = lane & 31;
    unsigned hb = (unsigned)(hl * 4);
    float4 bb = ((const float4*)b1)[hl];          // features 4hl..4hl+3
    int npairs = (n + 1) >> 1;
    for (int pw = blockIdx.x * 4 + wband; pw < npairs; pw += nwaves){
        int wid = pw * 2 + half;
        if (wid < n){
            size_t i = (size_t)wid;
            int start = off[wid], c = cnt[wid];
            unsigned v0 = *(const unsigned*)(hs + i * 128 + hb);
            floatx2 a01 = __builtin_amdgcn_cvt_pk_f32_fp8((int)v0, false);
            floatx2 a23 = __builtin_amdgcn_cvt_pk_f32_fp8((int)v0, true);
            int j = 0;
            for (; j + 8 <= c; j += 8){
                int i0 = start + j;
                unsigned o0 = (unsigned)__builtin_nontemporal_load(csr + i0 + 0) * 128u + hb;
                unsigned o1 = (unsigned)__builtin_nontemporal_load(csr + i0 + 1) * 128u + hb;
                unsigned o2 = (unsigned)__builtin_nontemporal_load(csr + i0 + 2) * 128u + hb;
                unsigned o3 = (unsigned)__builtin_nontemporal_load(csr + i0 + 3) * 128u + hb;
                unsigned o4 = (unsigned)__builtin_nontemporal_load(csr + i0 + 4) * 128u + hb;
                unsigned o5 = (unsigned)__builtin_nontemporal_load(csr + i0 + 5) * 128u + hb;
                unsigned o6 = (unsigned)__builtin_nontemporal_load(csr + i0 + 6) * 128u + hb;
                unsigned o7 = (unsigned)__builtin_nontemporal_load(csr + i0 + 7) * 128u + hb;
                unsigned w0 = *(const unsigned*)(hs + o0);
                unsigned w1 = *(const unsigned*)(hs + o1);
                unsigned w2 = *(const unsigned*)(hs + o2);
                unsigned w3 = *(const unsigned*)(hs + o3);
                unsigned w4 = *(const unsigned*)(hs + o4);
                unsigned w5 = *(const unsigned*)(hs + o5);
                unsigned w6 = *(const unsigned*)(hs + o6);
                unsigned w7 = *(const unsigned*)(hs + o7);
                a01 += __builtin_amdgcn_cvt_pk_f32_fp8((int)w0, false);
                a23 += __builtin_amdgcn_cvt_pk_f32_fp8((int)w0, true);
                a01 += __builtin_amdgcn_cvt_pk_f32_fp8((int)w1, false);
                a23 += __builtin_amdgcn_cvt_pk_f32_fp8((int)w1, true);
                a01 += __builtin_amdgcn_cvt_pk_f32_fp8((int)w2, false);
                a23 += __builtin_amdgcn_cvt_pk_f32_fp8((int)w2, true);
                a01 += __builtin_amdgcn_cvt_pk_f32_fp8((int)w3, false);
                a23 += __builtin_amdgcn_cvt_pk_f32_fp8((int)w3, true);
                a01 += __builtin_amdgcn_cvt_pk_f32_fp8((int)w4, false);
                a23 += __builtin_amdgcn_cvt_pk_f32_fp8((int)w4, true);
                a01 += __builtin_amdgcn_cvt_pk_f32_fp8((int)w5, false);
                a23 += __builtin_amdgcn_cvt_pk_f32_fp8((int)w5, true);
                a01 += __builtin_amdgcn_cvt_pk_f32_fp8((int)w6, false);
                a23 += __builtin_amdgcn_cvt_pk_f32_fp8((int)w6, true);
                a01 += __builtin_amdgcn_cvt_pk_f32_fp8((int)w7, false);
                a23 += __builtin_amdgcn_cvt_pk_f32_fp8((int)w7, true);
            }
            for (; j + 4 <= c; j += 4){
                int i0 = start + j;
                unsigned o0 = (unsigned)__builtin_nontemporal_load(csr + i0 + 0) * 128u + hb;
                unsigned o1 = (unsigned)__builtin_nontemporal_load(csr + i0 + 1) * 128u + hb;
                unsigned o2 = (unsigned)__builtin_nontemporal_load(csr + i0 + 2) * 128u + hb;
                unsigned o3 = (unsigned)__builtin_nontemporal_load(csr + i0 + 3) * 128u + hb;
                unsigned w0 = *(const unsigned*)(hs + o0);
                unsigned w1 = *(const unsigned*)(hs + o1);
                unsigned w2 = *(const unsigned*)(hs + o2);
                unsigned w3 = *(const unsigned*)(hs + o3);
                a01 += __builtin_amdgcn_cvt_pk_f32_fp8((int)w0, false);
                a23 += __builtin_amdgcn_cvt_pk_f32_fp8((int)w0, true);
                a01 += __builtin_amdgcn_cvt_pk_f32_fp8((int)w1, false);
                a23 += __builtin_amdgcn_cvt_pk_f32_fp8((int)w1, true);
                a01 += __builtin_amdgcn_cvt_pk_f32_fp8((int)w2, false);
                a23 += __builtin_amdgcn_cvt_pk_f32_fp8((int)w2, true);
                a01 += __builtin_amdgcn_cvt_pk_f32_fp8((int)w3, false);
                a23 += __builtin_amdgcn_cvt_pk_f32_fp8((int)w3, true);
            }
            for (; j < c; j++){
                unsigned o = (unsigned)__builtin_nontemporal_load(csr + start + j) * 128u + hb;
                unsigned wv = *(const unsigned*)(hs + o);
                a01 += __builtin_amdgcn_cvt_pk_f32_fp8((int)wv, false);
                a23 += __builtin_amdgcn_cvt_pk_f32_fp8((int)wv, true);
            }
            float dv = dinv[wid];
            float z0 = fmaxf(fmaf(dv, a01.x, bb.x), 0.f);
            float z1 = fmaxf(fmaf(dv, a01.y, bb.y), 0.f);
            float z2 = fmaxf(fmaf(dv, a23.x, bb.z), 0.f);
            float z3 = fmaxf(fmaf(dv, a23.y, bb.w), 0.f);
            zp[wband][half][hl * 2]     = __builtin_bit_cast(unsigned, __builtin_amdgcn_cvt_pkrtz(z0, z1));
            zp[wband][half][hl * 2 + 1] = __builtin_bit_cast(unsigned, __builtin_amdgcn_cvt_pkrtz(z2, z3));
            float acc0 = 0.f, acc1 = 0.f;
            #pragma unroll 16
            for (int kp = 0; kp < 64; kp++){
                h2 za = __builtin_bit_cast(h2, zp[wband][half][kp]);
                h2 wa = __builtin_bit_cast(h2, W2l[kp * 64 + hl]);
                h2 wb = __builtin_bit_cast(h2, W2l[kp * 64 + hl + 32]);
                acc0 = __builtin_amdgcn_fdot2(za, wa, acc0, false);
                acc1 = __builtin_amdgcn_fdot2(za, wb, acc1, false);
            }
            hs2[i * 64 + hl]      = f2b(acc0 * dv);
            hs2[i * 64 + hl + 32] = f2b(acc1 * dv);
        }
    }
}

// ---- aggregation layer 2: 4 nodes/wave, UNROLL 8 (32 rows in flight/wave) ----
__global__ __launch_bounds__(256) void k_agg2(const unsigned short* __restrict__ hs,
                                              const int* __restrict__ off,
                                              const int* __restrict__ cnt,
                                              const int* __restrict__ csr,
                                              const float* __restrict__ dinv,
                                              const float* __restrict__ b,
                                              unsigned short* __restrict__ z, int n){
    int wv = (blockIdx.x * 256 + threadIdx.x) >> 6;
    int lane = threadIdx.x & 63;
    int quarter = lane >> 4, ql = lane & 15;
    int node = wv * 4 + quarter;
    if (node >= n) return;
    size_t i = (size_t)node;
    const unsigned char* hb8 = (const unsigned char*)hs;
    unsigned qb = (unsigned)(ql * 8);
    int start = off[node], c = cnt[node];
    uint2 v0 = *(const uint2*)(hs + i * 64 + ql * 4);
    float a0 = b2f((unsigned short)v0.x), a1 = b2f((unsigned short)(v0.x >> 16));
    float a2 = b2f((unsigned short)v0.y), a3 = b2f((unsigned short)(v0.y >> 16));
    int j = 0;
    for (; j + 8 <= c; j += 8){
        int i0 = start + j;
        unsigned o0 = (unsigned)__builtin_nontemporal_load(csr + i0 + 0) * 128u + qb;
        unsigned o1 = (unsigned)__builtin_nontemporal_load(csr + i0 + 1) * 128u + qb;
        unsigned o2 = (unsigned)__builtin_nontemporal_load(csr + i0 + 2) * 128u + qb;
        unsigned o3 = (unsigned)__builtin_nontemporal_load(csr + i0 + 3) * 128u + qb;
        unsigned o4 = (unsigned)__builtin_nontemporal_load(csr + i0 + 4) * 128u + qb;
        unsigned o5 = (unsigned)__builtin_nontemporal_load(csr + i0 + 5) * 128u + qb;
        unsigned o6 = (unsigned)__builtin_nontemporal_load(csr + i0 + 6) * 128u + qb;
        unsigned o7 = (unsigned)__builtin_nontemporal_load(csr + i0 + 7) * 128u + qb;
        uint2 w0 = *(const uint2*)(hb8 + o0);
        uint2 w1 = *(const uint2*)(hb8 + o1);
        uint2 w2 = *(const uint2*)(hb8 + o2);
        uint2 w3 = *(const uint2*)(hb8 + o3);
        uint2 w4 = *(const uint2*)(hb8 + o4);
        uint2 w5 = *(const uint2*)(hb8 + o5);
        uint2 w6 = *(const uint2*)(hb8 + o6);
        uint2 w7 = *(const uint2*)(hb8 + o7);
        a0 += b2f((unsigned short)w0.x); a1 += b2f((unsigned short)(w0.x >> 16));
        a2 += b2f((unsigned short)w0.y); a3 += b2f((unsigned short)(w0.y >> 16));
        a0 += b2f((unsigned short)w1.x); a1 += b2f((unsigned short)(w1.x >> 16));
        a2 += b2f((unsigned short)w1.y); a3 += b2f((unsigned short)(w1.y >> 16));
        a0 += b2f((unsigned short)w2.x); a1 += b2f((unsigned short)(w2.x >> 16));
        a2 += b2f((unsigned short)w2.y); a3 += b2f((unsigned short)(w2.y >> 16));
        a0 += b2f((unsigned short)w3.x); a1 += b2f((unsigned short)(w3.x >> 16));
        a2 += b2f((unsigned short)w3.y); a3 += b2f((unsigned short)(w3.y >> 16));
        a0 += b2f((unsigned short)w4.x); a1 += b2f((unsigned short)(w4.x >> 16));
        a2 += b2f((unsigned short)w4.y); a3 += b2f((unsigned short)(w4.y >> 16));
        a0 += b2f((unsigned short)w5.x); a1 += b2f((unsigned short)(w5.x >> 16));
        a2 += b2f((unsigned short)w5.y); a3 += b2f((unsigned short)(w5.y >> 16));
        a0 += b2f((unsigned short)w6.x); a1 += b2f((unsigned short)(w6.x >> 16));
        a2 += b2f((unsigned short)w6.y); a3 += b2f((unsigned short)(w6.y >> 16));
        a0 += b2f((unsigned short)w7.x); a1 += b2f((unsigned short)(w7.x >> 16));
        a2 += b2f((unsigned short)w7.y); a3 += b2f((unsigned short)(w7.y >> 16));
    }
    for (; j + 4 <= c; j += 4){
        int i0 = start + j;
        unsigned o0 = (unsigned)__builtin_nontemporal_load(csr + i0 + 0) * 128u + qb;
        unsigned o1 = (unsigned)__builtin_nontemporal_load(csr + i0 + 1) * 128u + qb;
        unsigned o2 = (unsigned)__builtin_nontemporal_load(csr + i0 + 2) * 128u + qb;
        unsigned o3 = (unsigned)__builtin_nontemporal_load(csr + i0 + 3) * 128u + qb;
        uint2 w0 = *(const uint2*)(hb8 + o0);
        uint2 w1 = *(const uint2*)(hb8 + o1);
        uint2 w2 = *(const uint2*)(hb8 + o2);
        uint2 w3 = *(const uint2*)(hb8 + o3);
        a0 += b2f((unsigned short)w0.x); a1 += b2f((unsigned short)(w0.x >> 16));
        a2 += b2f((unsigned short)w0.y); a3 += b2f((unsigned short)(w0.y >> 16));
        a0 += b2f((unsigned short)w1.x); a1 += b2f((unsigned short)(w1.x >> 16));
        a2 += b2f((unsigned short)w1.y); a3 += b2f((unsigned short)(w1.y >> 16));
        a0 += b2f((unsigned short)w2.x); a1 += b2f((unsigned short)(w2.x >> 16));
        a2 += b2f((unsigned short)w2.y); a3 += b2f((unsigned short)(w2.y >> 16));
        a0 += b2f((unsigned short)w3.x); a1 += b2f((unsigned short)(w3.x >> 16));
        a2 += b2f((unsigned short)w3.y); a3 += b2f((unsigned short)(w3.y >> 16));
    }
    for (; j < c; j++){
        unsigned o = (unsigned)__builtin_nontemporal_load(csr + start + j) * 128u + qb;
        uint2 wv2 = *(const uint2*)(hb8 + o);
        a0 += b2f((unsigned short)wv2.x); a1 += b2f((unsigned short)(wv2.x >> 16));
        a2 += b2f((unsigned short)wv2.y); a3 += b2f((unsigned short)(wv2.y >> 16));
    }
    float dv = dinv[node];
    float4 bb = ((const float4*)b)[ql];
    float r0 = fmaf(dv, a0, bb.x);
    float r1 = fmaf(dv, a1, bb.y);
    float r2 = fmaf(dv, a2, bb.z);
    float r3 = fmaf(dv, a3, bb.w);
    uint2 ov;
    ov.x = (unsigned)f2b(r0) | ((unsigned)f2b(r1) << 16);
    ov.y = (unsigned)f2b(r2) | ((unsigned)f2b(r3) << 16);
    *(uint2*)(z + i * 64 + ql * 4) = ov;
}

// ------- decode: out[e] = dot(z2[s], z2[t]); 8 edges/wave, uint4 loads ---------
__global__ __launch_bounds__(256) void k_decode(const unsigned short* __restrict__ z,
                                                const int* __restrict__ es,
                                                const int* __restrict__ et,
                                                float* __restrict__ out, int m){
    int wv = (blockIdx.x * 256 + threadIdx.x) >> 6;
    int lane = threadIdx.x & 63;
    int e = wv * 8 + (lane >> 3);
    int o8 = lane & 7;
    float p = 0.f;
    if (e < m){
        size_t s = (size_t)es[e], t2 = (size_t)et[e];
        uint4 vs = *(const uint4*)(z + s * 64 + o8 * 8);
        uint4 vt = *(const uint4*)(z + t2 * 64 + o8 * 8);
        p = b2f((unsigned short)vs.x) * b2f((unsigned short)vt.x)
          + b2f((unsigned short)(vs.x >> 16)) * b2f((unsigned short)(vt.x >> 16))
          + b2f((unsigned short)vs.y) * b2f((unsigned short)vt.y)
          + b2f((unsigned short)(vs.y >> 16)) * b2f((unsigned short)(vt.y >> 16))
          + b2f((unsigned short)vs.z) * b2f((unsigned short)vt.z)
          + b2f((unsigned short)(vs.z >> 16)) * b2f((unsigned short)(vt.z >> 16))
          + b2f((unsigned short)vs.w) * b2f((unsigned short)vt.w)
          + b2f((unsigned short)(vs.w >> 16)) * b2f((unsigned short)(vt.w >> 16));
    }
    #pragma unroll
    for (int o = 4; o > 0; o >>= 1) p += __shfl_xor(p, o);
    if (o8 == 0 && e < m) out[e] = p;
}

// ---------------- launcher (round-0 workspace layout, 46.07MB) ----------------

extern "C" void kernel_launch(void* const* d_in, const int* in_sizes, int n_in,
                              void* d_out, int out_size, void* d_ws, size_t ws_size,
                              hipStream_t stream){
    const float* x   = (const float*)d_in[0];
    const int*   ei  = (const int*)d_in[1];
    const int*   eli = (const int*)d_in[2];
    const float* W1  = (const float*)d_in[3];
    const float* b1  = (const float*)d_in[4];
    const float* W2  = (const float*)d_in[5];
    const float* b2  = (const float*)d_in[6];
    float* out = (float*)d_out;

    int N_  = in_sizes[0] / 128;
    int E_  = in_sizes[1] / 2;
    int EL_ = in_sizes[2] / 2;
    int NBINS = (N_ + 127) >> 7;           // 782 for N=100k (must be <= 1024)
    const int EPB = 4096;
    int NBLK = (E_ + EPB - 1) / EPB;       // 391 for E=1.6M

    char* w = (char*)d_ws;
    size_t o = 0;
    auto alloc = [&](size_t bytes) -> size_t {
        size_t r = o; o += (bytes + 511) & ~(size_t)511; return r;
    };
    size_t o_cnt  = alloc((size_t)N_ * 4);
    size_t o_off  = alloc((size_t)N_ * 4);
    size_t o_dinv = alloc((size_t)N_ * 4);
    size_t o_gcur = alloc((size_t)NBINS * 4);
    size_t o_csr  = alloc((size_t)E_ * 4);
    size_t o_wf1  = alloc(16384 * 2);
    size_t o_w2p  = alloc(4096 * 4);
    size_t o_slab = alloc((size_t)NBINS * 4096 * 4);   // 12.8MB; also z2 after binsort+agg2
    size_t o_hs1  = alloc((size_t)N_ * 128);           // fp8 table, 12.8MB
    size_t o_hs2  = alloc((size_t)N_ * 64 * 2);        // bf16 table, 12.8MB

    int* cnt  = (int*)(w + o_cnt);
    int* off  = (int*)(w + o_off);
    float* dinv = (float*)(w + o_dinv);
    int* gcur = (int*)(w + o_gcur);
    int* csr  = (int*)(w + o_csr);
    unsigned short* wf1 = (unsigned short*)(w + o_wf1);
    unsigned* w2p = (unsigned*)(w + o_w2p);
    unsigned* slab = (unsigned*)(w + o_slab);
    unsigned char* hs1 = (unsigned char*)(w + o_hs1);
    unsigned short* hs2 = (unsigned short*)(w + o_hs2);
    unsigned short* z2  = (unsigned short*)(w + o_slab);  // slab dead after binsort

    const int AGG1_BLOCKS = 2048;          // 8 blocks/CU (18KB LDS) -> 32 waves/CU
    int nwaves = AGG1_BLOCKS * 4;

    k_init    <<<25, 256, 0, stream>>>(W1, W2, wf1, w2p, gcur, NBINS);
    k_scatter2<<<NBLK, 256, 0, stream>>>(ei, ei + E_, gcur, slab, E_, NBINS);
    k_binsort <<<NBINS, 256, 0, stream>>>(slab, gcur, csr, cnt, off, dinv, N_, NBINS);
    k_gemm1   <<<(N_ + 63) / 64, 256, 0, stream>>>(x, wf1, dinv, hs1, N_);
    k_agg1g2  <<<AGG1_BLOCKS, 256, 0, stream>>>(hs1, off, cnt, csr, dinv, b1, w2p, hs2, N_, nwaves);
    k_agg2    <<<(N_ + 15) / 16, 256, 0, stream>>>(hs2, off, cnt, csr, dinv, b2, z2, N_);
    k_decode  <<<(EL_ + 31) / 32, 256, 0, stream>>>(z2, eli, eli + EL_, out, EL_);
}